// Round 11
// baseline (519.943 us; speedup 1.0000x reference)
//
#include <hip/hip_runtime.h>
#include <hip/hip_bf16.h>

typedef __attribute__((ext_vector_type(8))) short short8;
typedef __attribute__((ext_vector_type(4))) float f32x4;

#define B_    8
#define N_    4097
#define C_    768
#define M_TOT (B_*N_)      /* 32776 */
#define K3    (3*C_)       /* 2304  */
#define CHUNKS 16
#define NSTEP 24           /* 768/32 K-steps */

__device__ __forceinline__ float bf2f(unsigned short u) {
  union { unsigned int i; float f; } x; x.i = ((unsigned int)u) << 16; return x.f;
}
__device__ __forceinline__ unsigned short f2bf(float f) {
  union { float f; unsigned int i; } x; x.f = f;
  unsigned int i = x.i + 0x7fffu + ((x.i >> 16) & 1u);
  return (unsigned short)(i >> 16);
}
__device__ __forceinline__ void gload16(const void* g, void* l) {
  __builtin_amdgcn_global_load_lds(
      (const __attribute__((address_space(1))) void*)g,
      (__attribute__((address_space(3))) void*)l, 16, 0, 0);
}

// ---------------- fp32 -> bf16 convert (qkv_w only) ----------------
__global__ __launch_bounds__(256) void cvt_kernel(const float* __restrict__ in,
                                                  unsigned short* __restrict__ out,
                                                  long n4) {
  long i = (long)blockIdx.x * blockDim.x + threadIdx.x;
  long stride = (long)gridDim.x * blockDim.x;
  for (; i < n4; i += stride) {
    float4 v = ((const float4*)in)[i];
    ushort4 o;
    o.x = f2bf(v.x); o.y = f2bf(v.y); o.z = f2bf(v.z); o.w = f2bf(v.w);
    ((ushort4*)out)[i] = o;
  }
}

// ============ GEMM1: qkv = x @ qkv_w^T  (128x256, ring-3 BK=32) ============
// A reg-staged from fp32 x (fused cvt); B via global_load_lds (bf16).
// slot: [0,8K) A(128x32) lane-linear; [8K,24K) B(256x32) lane-linear. 72KB total.
__global__ __launch_bounds__(512, 4) void gemm_qkv_rope(
    const float* __restrict__ X,             // [32776,768] fp32
    const unsigned short* __restrict__ Bw,   // [2304,768] bf16
    const float* __restrict__ rope,          // [4096,128] sin||cos
    const float* __restrict__ qb,
    const float* __restrict__ vb,
    unsigned short* __restrict__ qkv)        // planes [3][32776][768]
{
  __shared__ __align__(16) char L[3*24576];
  const int tid  = threadIdx.x;
  const int wave = tid >> 6, lane = tid & 63;
  const int lr = lane & 15, lk = lane >> 4;
  const int wm = wave >> 2, wn = wave & 3;   // 2m x 4n waves, each 64x64 out

  // bijective XCD swizzle: nwg = 2313, q=289, r=1; n-fastest (R6 order)
  const int o = blockIdx.x;
  const int xcd = o & 7, loc = o >> 3;
  const int tile = (xcd < 1 ? xcd*290 : 290 + (xcd-1)*289) + loc;
  const int m0 = (tile / 9) * 128;
  const int n0 = (tile % 9) * 256;

  // staging: thread t covers row wave*16+lr, k-chunk lk (8 elems); dest = tid*16
  const int arow = wave*16 + lr;
  const int am = min(m0 + arow, M_TOT-1);
  const float*          gX  = X  + (long)am*768 + lk*8;
  const unsigned short* gB1 = Bw + (long)(n0 + arow)*768 + lk*8;
  const unsigned short* gB2 = Bw + (long)(n0 + 128 + arow)*768 + lk*8;
  const int dA  = tid*16;
  const int dB1 = 8192  + tid*16;
  const int dB2 = 16384 + tid*16;

  // fragment reads: contiguous 1KB per wave (conflict-free)
  const int abase = (wm*4)*1024 + lane*16;
  const int bbase = 8192 + (wn*4)*1024 + lane*16;

  f32x4 acc[4][4];
#pragma unroll
  for (int i = 0; i < 4; ++i)
#pragma unroll
    for (int j = 0; j < 4; ++j) acc[i][j] = (f32x4){0.f,0.f,0.f,0.f};

  auto STAGE_B = [&](int buf, int kk) {
    char* sb = L + buf*24576;
    gload16(gB1 + kk, sb + dB1);
    gload16(gB2 + kk, sb + dB2);
  };
  auto WRITE_A = [&](int buf, const float4& fa, const float4& fb) {
    short8 v;
    v[0]=(short)f2bf(fa.x); v[1]=(short)f2bf(fa.y); v[2]=(short)f2bf(fa.z); v[3]=(short)f2bf(fa.w);
    v[4]=(short)f2bf(fb.x); v[5]=(short)f2bf(fb.y); v[6]=(short)f2bf(fb.z); v[7]=(short)f2bf(fb.w);
    *(short8*)(L + buf*24576 + dA) = v;
  };
  auto COMPUTE = [&](int buf) {
    const char* sb = L + buf*24576;
    short8 af[4], bfr[4];
#pragma unroll
    for (int mi = 0; mi < 4; ++mi)
      af[mi] = *(const short8*)(sb + abase + mi*1024);
#pragma unroll
    for (int ni = 0; ni < 4; ++ni)
      bfr[ni] = *(const short8*)(sb + bbase + ni*1024);
#pragma unroll
    for (int mi = 0; mi < 4; ++mi)
#pragma unroll
      for (int ni = 0; ni < 4; ++ni)
        acc[mi][ni] = __builtin_amdgcn_mfma_f32_16x16x32_bf16(af[mi], bfr[ni], acc[mi][ni], 0, 0, 0);
  };

  // ---- prologue: fill slots 0,1 ----
  {
    float4 a00 = *(const float4*)(gX + 0), a01 = *(const float4*)(gX + 4);
    __builtin_amdgcn_sched_barrier(0);
    STAGE_B(0, 0);
    __builtin_amdgcn_sched_barrier(0);
    float4 a10 = *(const float4*)(gX + 32), a11 = *(const float4*)(gX + 36);
    __builtin_amdgcn_sched_barrier(0);
    STAGE_B(1, 32);
    __builtin_amdgcn_sched_barrier(0);
    asm volatile("s_waitcnt vmcnt(6)" ::: "memory");   // A0 landed
    WRITE_A(0, a00, a01);
    asm volatile("s_waitcnt vmcnt(2)" ::: "memory");   // B0, A1 landed (B1 in flight)
    WRITE_A(1, a10, a11);
    asm volatile("s_waitcnt lgkmcnt(0)" ::: "memory");
    __builtin_amdgcn_s_barrier();
    __builtin_amdgcn_sched_barrier(0);
  }

  int cur = 0;
  for (int tt = 0; tt < NSTEP-2; ++tt) {
    int stg = cur + 2; if (stg >= 3) stg -= 3;
    const int kk = (tt+2)*32;
    float4 fa0 = *(const float4*)(gX + kk), fa1 = *(const float4*)(gX + kk + 4);
    __builtin_amdgcn_sched_barrier(0);
    STAGE_B(stg, kk);
    __builtin_amdgcn_sched_barrier(0);
    COMPUTE(cur);
    asm volatile("s_waitcnt vmcnt(2)" ::: "memory");   // A(t) + B(t-1) landed; B(t) in flight
    __builtin_amdgcn_sched_barrier(0);
    WRITE_A(stg, fa0, fa1);
    asm volatile("s_waitcnt lgkmcnt(0)" ::: "memory");
    __builtin_amdgcn_s_barrier();
    __builtin_amdgcn_sched_barrier(0);
    cur = (cur + 1 == 3) ? 0 : cur + 1;
  }
  COMPUTE(cur);                                        // step NSTEP-2
  asm volatile("s_waitcnt vmcnt(0)" ::: "memory");
  __builtin_amdgcn_s_barrier();
  __builtin_amdgcn_sched_barrier(0);
  cur = (cur + 1 == 3) ? 0 : cur + 1;
  COMPUTE(cur);                                        // step NSTEP-1

  // ---- epilogue: bias (+RoPE for q/k) + bf16 store to planes (cached stores) ----
  const int which = n0 / 768;                 // block-uniform (768 % 256 == 0)
  unsigned short* plane = qkv + (long)which*M_TOT*768;

  float biasv[4]; int withv[4]; int dv[4];
#pragma unroll
  for (int ni = 0; ni < 4; ++ni) {
    const int gc = n0 + wn*64 + ni*16 + lr;
    const int within = gc - which*768;
    withv[ni] = within;
    dv[ni] = within & 63;
    biasv[ni] = (which == 0) ? qb[within] : (which == 2 ? vb[within] : 0.f);
  }

  if (which == 2) {                           // V: no rope, no shfl, no %
#pragma unroll
    for (int mi = 0; mi < 4; ++mi)
#pragma unroll
      for (int r = 0; r < 4; ++r) {
        const int gm = m0 + wm*64 + mi*16 + lk*4 + r;
        if (gm < M_TOT) {
#pragma unroll
          for (int ni = 0; ni < 4; ++ni)
            plane[(long)gm*768 + withv[ni]] = f2bf(acc[mi][ni][r] + biasv[ni]);
        }
      }
  } else {                                    // Q/K: rope
#pragma unroll
    for (int mi = 0; mi < 4; ++mi) {
#pragma unroll
      for (int r = 0; r < 4; ++r) {
        const int gm = m0 + wm*64 + mi*16 + lk*4 + r;
        const int ntok = gm % 4097;           // once per (mi,r)
        const bool valid = gm < M_TOT;
        const bool dorope = (ntok > 0) && valid;
        const float* rp = rope + (long)(ntok - 1)*128;
#pragma unroll
        for (int ni = 0; ni < 4; ++ni) {
          float v = acc[mi][ni][r] + biasv[ni];
          float pair = __shfl_xor(v, 1);      // col d^1 lives in lane^1
          float vo = v;
          if (dorope) {
            const float s = rp[dv[ni]], c = rp[64 + dv[ni]];
            const float rot = (dv[ni] & 1) ? pair : -pair;
            vo = v*c + rot*s;
          }
          if (valid) plane[(long)gm*768 + withv[ni]] = f2bf(vo);
        }
      }
    }
  }
}

// ---------------- kv partials: kv[b,h] = K^T V over an N-chunk ----------------
__global__ __launch_bounds__(256) void kv_partial_kernel(
    const unsigned short* __restrict__ qkv, float* __restrict__ part)
{
  const int bh = blockIdx.y;
  const int b = bh / 12, h = bh % 12;
  const int chunk = blockIdx.x;
  const int per = (N_ + CHUNKS - 1) / CHUNKS;
  const int nst = chunk * per;
  const int nen = min(nst + per, N_);
  const unsigned short* Kpl = qkv + (long)M_TOT*768 + ((long)b*N_)*768 + h*64;
  const unsigned short* Vpl = qkv + (long)2*M_TOT*768 + ((long)b*N_)*768 + h*64;
  __shared__ unsigned short Kl[32*64];
  __shared__ unsigned short Vl[32*64];
  const int t = threadIdx.x;
  const int ty = t >> 4, tx = t & 15;
  const int lrow = t >> 3, lpc = t & 7;
  float acc[4][4] = {};
  for (int nb = nst; nb < nen; nb += 32) {
    const int cnt = min(32, nen - nb);
    __syncthreads();
    if (lrow < cnt) {
      *(uint4*)(Kl + lrow*64 + lpc*8) = *(const uint4*)(Kpl + (long)(nb + lrow)*768 + lpc*8);
      *(uint4*)(Vl + lrow*64 + lpc*8) = *(const uint4*)(Vpl + (long)(nb + lrow)*768 + lpc*8);
    }
    __syncthreads();
#pragma unroll 2
    for (int i = 0; i < cnt; ++i) {
      const ushort4 ku = *(const ushort4*)(Kl + i*64 + ty*4);
      const ushort4 vu = *(const ushort4*)(Vl + i*64 + tx*4);
      float kf[4] = {bf2f(ku.x), bf2f(ku.y), bf2f(ku.z), bf2f(ku.w)};
      float vf[4] = {bf2f(vu.x), bf2f(vu.y), bf2f(vu.z), bf2f(vu.w)};
#pragma unroll
      for (int a = 0; a < 4; ++a)
#pragma unroll
        for (int e = 0; e < 4; ++e) acc[a][e] += kf[a]*vf[e];
    }
  }
  float* dst = part + ((long)chunk*96 + bh)*4096 + (ty*4)*64 + tx*4;
#pragma unroll
  for (int a = 0; a < 4; ++a)
#pragma unroll
    for (int e = 0; e < 4; ++e) dst[a*64 + e] = acc[a][e];
}

// ---- McombT[b][c][h*64+d] = sum_e kv[b,h,d,e]*pw[c,h*64+e] / (hd*N) ----
__global__ __launch_bounds__(256) void mcomb_kernel(const float* __restrict__ part,
                                                    const float* __restrict__ pw,
                                                    unsigned short* __restrict__ McT) {
  const int blk = blockIdx.x;            // 8*12*2 = 192
  const int cs = blk & 1;
  const int h  = (blk >> 1) % 12;
  const int b  = blk / 24;
  const int bh = b*12 + h;
  __shared__ float kvs[64][65];          // kvs[e][d]
  const int t = threadIdx.x;
  const int d_own = t >> 2;
  const int eg = (t & 3) * 16;

  float4 a0 = {0,0,0,0}, a1 = {0,0,0,0}, a2 = {0,0,0,0}, a3 = {0,0,0,0};
  const float4* p4 = (const float4*)part;
#pragma unroll
  for (int ch = 0; ch < CHUNKS; ++ch) {
    const long base = ((long)ch*96 + bh)*1024 + d_own*16 + (t & 3)*4;
    float4 v0 = p4[base+0], v1 = p4[base+1], v2 = p4[base+2], v3 = p4[base+3];
    a0.x += v0.x; a0.y += v0.y; a0.z += v0.z; a0.w += v0.w;
    a1.x += v1.x; a1.y += v1.y; a1.z += v1.z; a1.w += v1.w;
    a2.x += v2.x; a2.y += v2.y; a2.z += v2.z; a2.w += v2.w;
    a3.x += v3.x; a3.y += v3.y; a3.z += v3.z; a3.w += v3.w;
  }
  kvs[eg+ 0][d_own] = a0.x; kvs[eg+ 1][d_own] = a0.y; kvs[eg+ 2][d_own] = a0.z; kvs[eg+ 3][d_own] = a0.w;
  kvs[eg+ 4][d_own] = a1.x; kvs[eg+ 5][d_own] = a1.y; kvs[eg+ 6][d_own] = a1.z; kvs[eg+ 7][d_own] = a1.w;
  kvs[eg+ 8][d_own] = a2.x; kvs[eg+ 9][d_own] = a2.y; kvs[eg+10][d_own] = a2.z; kvs[eg+11][d_own] = a2.w;
  kvs[eg+12][d_own] = a3.x; kvs[eg+13][d_own] = a3.y; kvs[eg+14][d_own] = a3.z; kvs[eg+15][d_own] = a3.w;
  __syncthreads();

  const int lane = t & 63;
  const int w    = t >> 6;
  float kvcol[64];
#pragma unroll
  for (int e = 0; e < 64; ++e) kvcol[e] = kvs[e][lane];

  const float scale = (float)(1.0/(64.0*4097.0));
  const int cbase = cs*384 + w*96;
  for (int i = 0; i < 96; ++i) {
    const int c = cbase + i;
    const float* pwrow = pw + (long)c*768 + h*64;
    float s = 0.f;
#pragma unroll
    for (int e = 0; e < 64; ++e) s += pwrow[e] * kvcol[e];
    McT[((long)b*768 + c)*768 + h*64 + lane] = f2bf(s * scale);
  }
}

// ============ GEMM2: out[b] = Q[b] @ McT[b]^T + proj_b (128x256, ring-3, lane-linear) ============
__global__ __launch_bounds__(512, 4) void gemm_final(
    const unsigned short* __restrict__ qkv,   // q plane = first M_TOT*768
    const unsigned short* __restrict__ McT,   // [8,768,768] bf16
    const float* __restrict__ pb,
    float* __restrict__ out)
{
  __shared__ __align__(16) char L[3*24576];
  const int tid  = threadIdx.x;
  const int wave = tid >> 6, lane = tid & 63;
  const int lr = lane & 15, lk = lane >> 4;
  const int wm = wave >> 2, wn = wave & 3;

  // XCD swizzle: nwg = 8*33*3 = 792 (one batch per XCD); ct-fastest (R6 order)
  const int o = blockIdx.x;
  const int xcd = o & 7, loc = o >> 3;
  const int b  = xcd;
  const int mt = loc / 3, ct = loc % 3;
  const int m0 = mt * 128;
  const int c0 = ct * 256;

  const int arow = wave*16 + lr;
  const int achk = lk;
  const int am = min(m0 + arow, N_-1);
  const unsigned short* gA  = qkv + ((long)b*N_ + am)*768 + achk*8;
  const unsigned short* Bb  = McT + (long)b*768*768;
  const unsigned short* gB1 = Bb + (long)(c0 + arow)*768 + achk*8;
  const unsigned short* gB2 = Bb + (long)(c0 + 128 + arow)*768 + achk*8;
  const int dA  = tid*16;
  const int dB1 = 8192  + tid*16;
  const int dB2 = 16384 + tid*16;

  const int abase = (wm*4)*1024 + lane*16;
  const int bbase = 8192 + (wn*4)*1024 + lane*16;

  f32x4 acc[4][4];
#pragma unroll
  for (int i = 0; i < 4; ++i)
#pragma unroll
    for (int j = 0; j < 4; ++j) acc[i][j] = (f32x4){0.f,0.f,0.f,0.f};

  auto STAGE = [&](int buf, int kk) {
    char* sb = L + buf*24576;
    gload16(gA  + kk, sb + dA);
    gload16(gB1 + kk, sb + dB1);
    gload16(gB2 + kk, sb + dB2);
  };
  auto COMPUTE = [&](int buf) {
    const char* sb = L + buf*24576;
    short8 af[4], bfr[4];
#pragma unroll
    for (int mi = 0; mi < 4; ++mi)
      af[mi] = *(const short8*)(sb + abase + mi*1024);
#pragma unroll
    for (int ni = 0; ni < 4; ++ni)
      bfr[ni] = *(const short8*)(sb + bbase + ni*1024);
#pragma unroll
    for (int mi = 0; mi < 4; ++mi)
#pragma unroll
      for (int ni = 0; ni < 4; ++ni)
        acc[mi][ni] = __builtin_amdgcn_mfma_f32_16x16x32_bf16(af[mi], bfr[ni], acc[mi][ni], 0, 0, 0);
  };

  STAGE(0, 0);
  STAGE(1, 32);
  asm volatile("s_waitcnt vmcnt(3)" ::: "memory");
  __builtin_amdgcn_s_barrier();
  __builtin_amdgcn_sched_barrier(0);

  int cur = 0;
  for (int tt = 0; tt < NSTEP-2; ++tt) {
    int stg = cur + 2; if (stg >= 3) stg -= 3;
    STAGE(stg, (tt+2)*32);
    COMPUTE(cur);
    asm volatile("s_waitcnt vmcnt(3)" ::: "memory");
    __builtin_amdgcn_sched_barrier(0);
    __builtin_amdgcn_s_barrier();
    __builtin_amdgcn_sched_barrier(0);
    cur = (cur + 1 == 3) ? 0 : cur + 1;
  }
  COMPUTE(cur);
  asm volatile("s_waitcnt vmcnt(0)" ::: "memory");
  __builtin_amdgcn_sched_barrier(0);
  __builtin_amdgcn_s_barrier();
  __builtin_amdgcn_sched_barrier(0);
  cur = (cur + 1 == 3) ? 0 : cur + 1;
  COMPUTE(cur);

#pragma unroll
  for (int mi = 0; mi < 4; ++mi) {
#pragma unroll
    for (int ni = 0; ni < 4; ++ni) {
      const int gc = c0 + wn*64 + ni*16 + lr;
      const float bias = pb[gc];
#pragma unroll
      for (int r = 0; r < 4; ++r) {
        const int tok = m0 + wm*64 + mi*16 + lk*4 + r;
        if (tok < N_)
          __builtin_nontemporal_store(acc[mi][ni][r] + bias,
                                      out + ((long)b*N_ + tok)*768 + gc);
      }
    }
  }
}

extern "C" void kernel_launch(void* const* d_in, const int* in_sizes, int n_in,
                              void* d_out, int out_size, void* d_ws, size_t ws_size,
                              hipStream_t stream) {
  const float* x      = (const float*)d_in[0];
  const float* rope   = (const float*)d_in[1];
  const float* qkv_w  = (const float*)d_in[2];
  const float* q_bias = (const float*)d_in[3];
  const float* v_bias = (const float*)d_in[4];
  const float* proj_w = (const float*)d_in[5];
  const float* proj_b = (const float*)d_in[6];
  float* out = (float*)d_out;

  // workspace: non-overlapping regions (R8 lesson)
  char* w0 = (char*)d_ws;
  unsigned short* wq_bf = (unsigned short*)w0;                 //  3,538,944 B
  float*          part  = (float*)(w0 + 4194304);              // 25,165,824 B
  unsigned short* McT   = (unsigned short*)(w0 + 29360128);    //  9,437,184 B
  unsigned short* qkv   = (unsigned short*)(w0 + 41943040);    // 151,031,808 B

  cvt_kernel<<<1728, 256, 0, stream>>>(qkv_w, wq_bf, (long)K3*768/4);

  gemm_qkv_rope<<<2313, 512, 0, stream>>>(x, wq_bf, rope, q_bias, v_bias, qkv);

  kv_partial_kernel<<<dim3(CHUNKS, 96), 256, 0, stream>>>(qkv, part);
  mcomb_kernel<<<192, 256, 0, stream>>>(part, proj_w, McT);

  gemm_final<<<792, 512, 0, stream>>>(qkv, McT, proj_b, out);
}

// Round 12
// 451.947 us; speedup vs baseline: 1.1505x; 1.1505x over previous
//
#include <hip/hip_runtime.h>
#include <hip/hip_bf16.h>

typedef __attribute__((ext_vector_type(8))) short short8;
typedef __attribute__((ext_vector_type(4))) float f32x4;

#define B_    8
#define N_    4097
#define C_    768
#define M_TOT (B_*N_)      /* 32776 */
#define K3    (3*C_)       /* 2304  */
#define CHUNKS 16
#define NSTEP 24           /* 768/32 K-steps */

__device__ __forceinline__ float bf2f(unsigned short u) {
  union { unsigned int i; float f; } x; x.i = ((unsigned int)u) << 16; return x.f;
}
__device__ __forceinline__ unsigned short f2bf(float f) {
  union { float f; unsigned int i; } x; x.f = f;
  unsigned int i = x.i + 0x7fffu + ((x.i >> 16) & 1u);
  return (unsigned short)(i >> 16);
}
__device__ __forceinline__ void gload16(const void* g, void* l) {
  __builtin_amdgcn_global_load_lds(
      (const __attribute__((address_space(1))) void*)g,
      (__attribute__((address_space(3))) void*)l, 16, 0, 0);
}

// ---------------- fp32 -> bf16 convert (x then qkv_w, one kernel) ----------------
__global__ __launch_bounds__(256) void cvt_kernel(const float* __restrict__ inx,
                                                  unsigned short* __restrict__ outx,
                                                  const float* __restrict__ inw,
                                                  unsigned short* __restrict__ outw,
                                                  long n4x, long n4tot) {
  long i = (long)blockIdx.x * blockDim.x + threadIdx.x;
  long stride = (long)gridDim.x * blockDim.x;
  for (; i < n4tot; i += stride) {
    const float4* src; ushort4* dst; long j;
    if (i < n4x) { src = (const float4*)inx; dst = (ushort4*)outx; j = i; }
    else         { src = (const float4*)inw; dst = (ushort4*)outw; j = i - n4x; }
    float4 v = src[j];
    ushort4 o;
    o.x = f2bf(v.x); o.y = f2bf(v.y); o.z = f2bf(v.z); o.w = f2bf(v.w);
    dst[j] = o;
  }
}

// ============ GEMM1: qkv = x @ qkv_w^T  (128x256, ring-3 BK=32, lane-linear LDS) ============
// slot: [0,8K) A(128x32) 8 groups x 1KB lane-linear; [8K,24K) B(256x32) 16 groups. 72KB.
__global__ __launch_bounds__(512, 4) void gemm_qkv_rope(
    const unsigned short* __restrict__ A,    // [32776,768]
    const unsigned short* __restrict__ Bw,   // [2304,768]
    const float* __restrict__ rope,          // [4096,128] sin||cos
    const float* __restrict__ qb,
    const float* __restrict__ vb,
    unsigned short* __restrict__ qkv)        // planes [3][32776][768]
{
  __shared__ __align__(16) char L[3*24576];
  const int tid  = threadIdx.x;
  const int wave = tid >> 6, lane = tid & 63;
  const int lr = lane & 15, lk = lane >> 4;
  const int wm = wave >> 2, wn = wave & 3;   // 2m x 4n waves, each 64x64 out

  // bijective XCD swizzle: nwg = 2313, q=289, r=1; n-fastest (R6 order)
  const int o = blockIdx.x;
  const int xcd = o & 7, loc = o >> 3;
  const int tile = (xcd < 1 ? xcd*290 : 290 + (xcd-1)*289) + loc;
  const int m0 = (tile / 9) * 128;
  const int n0 = (tile % 9) * 256;

  // staging: thread t covers row wave*16+lr, k-chunk lk (8 elems); dest = tid*16
  const int arow = wave*16 + lr;
  const int am = min(m0 + arow, M_TOT-1);
  const unsigned short* gA  = A  + (long)am*768 + lk*8;
  const unsigned short* gB1 = Bw + (long)(n0 + arow)*768 + lk*8;
  const unsigned short* gB2 = Bw + (long)(n0 + 128 + arow)*768 + lk*8;
  const int dA  = tid*16;
  const int dB1 = 8192  + tid*16;
  const int dB2 = 16384 + tid*16;

  // fragment reads: contiguous 1KB per wave-group (conflict-free)
  const int abase = (wm*4)*1024 + lane*16;
  const int bbase = 8192 + (wn*4)*1024 + lane*16;

  f32x4 acc[4][4];
#pragma unroll
  for (int i = 0; i < 4; ++i)
#pragma unroll
    for (int j = 0; j < 4; ++j) acc[i][j] = (f32x4){0.f,0.f,0.f,0.f};

  auto STAGE = [&](int buf, int kk) {
    char* sb = L + buf*24576;
    gload16(gA  + kk, sb + dA);
    gload16(gB1 + kk, sb + dB1);
    gload16(gB2 + kk, sb + dB2);
  };
  auto COMPUTE = [&](int buf) {
    const char* sb = L + buf*24576;
    short8 af[4], bfr[4];
#pragma unroll
    for (int mi = 0; mi < 4; ++mi)
      af[mi] = *(const short8*)(sb + abase + mi*1024);
#pragma unroll
    for (int ni = 0; ni < 4; ++ni)
      bfr[ni] = *(const short8*)(sb + bbase + ni*1024);
#pragma unroll
    for (int mi = 0; mi < 4; ++mi)
#pragma unroll
      for (int ni = 0; ni < 4; ++ni)
        acc[mi][ni] = __builtin_amdgcn_mfma_f32_16x16x32_bf16(af[mi], bfr[ni], acc[mi][ni], 0, 0, 0);
  };

  STAGE(0, 0);
  STAGE(1, 32);
  asm volatile("s_waitcnt vmcnt(3)" ::: "memory");
  __builtin_amdgcn_s_barrier();
  __builtin_amdgcn_sched_barrier(0);

  int cur = 0;
  for (int tt = 0; tt < NSTEP-2; ++tt) {
    int stg = cur + 2; if (stg >= 3) stg -= 3;
    STAGE(stg, (tt+2)*32);
    COMPUTE(cur);
    asm volatile("s_waitcnt vmcnt(3)" ::: "memory");
    __builtin_amdgcn_sched_barrier(0);
    __builtin_amdgcn_s_barrier();
    __builtin_amdgcn_sched_barrier(0);
    cur = (cur + 1 == 3) ? 0 : cur + 1;
  }
  COMPUTE(cur);
  asm volatile("s_waitcnt vmcnt(0)" ::: "memory");
  __builtin_amdgcn_sched_barrier(0);
  __builtin_amdgcn_s_barrier();
  __builtin_amdgcn_sched_barrier(0);
  cur = (cur + 1 == 3) ? 0 : cur + 1;
  COMPUTE(cur);

  // ---- epilogue: bias (+RoPE for q/k) + bf16 store to planes ----
  const int which = n0 / 768;                 // block-uniform (768 % 256 == 0)
  unsigned short* plane = qkv + (long)which*M_TOT*768;

  float biasv[4]; int withv[4]; int dv[4];
#pragma unroll
  for (int ni = 0; ni < 4; ++ni) {
    const int gc = n0 + wn*64 + ni*16 + lr;
    const int within = gc - which*768;
    withv[ni] = within;
    dv[ni] = within & 63;
    biasv[ni] = (which == 0) ? qb[within] : (which == 2 ? vb[within] : 0.f);
  }

  if (which == 2) {                           // V: no rope, no shfl, no %
#pragma unroll
    for (int mi = 0; mi < 4; ++mi)
#pragma unroll
      for (int r = 0; r < 4; ++r) {
        const int gm = m0 + wm*64 + mi*16 + lk*4 + r;
        if (gm < M_TOT) {
#pragma unroll
          for (int ni = 0; ni < 4; ++ni)
            plane[(long)gm*768 + withv[ni]] = f2bf(acc[mi][ni][r] + biasv[ni]);
        }
      }
  } else {                                    // Q/K: rope
#pragma unroll
    for (int mi = 0; mi < 4; ++mi) {
#pragma unroll
      for (int r = 0; r < 4; ++r) {
        const int gm = m0 + wm*64 + mi*16 + lk*4 + r;
        const int ntok = gm % 4097;           // once per (mi,r)
        const bool valid = gm < M_TOT;
        const bool dorope = (ntok > 0) && valid;
        const float* rp = rope + (long)(ntok - 1)*128;
#pragma unroll
        for (int ni = 0; ni < 4; ++ni) {
          float v = acc[mi][ni][r] + biasv[ni];
          float pair = __shfl_xor(v, 1);      // col d^1 lives in lane^1
          float vo = v;
          if (dorope) {
            const float s = rp[dv[ni]], c = rp[64 + dv[ni]];
            const float rot = (dv[ni] & 1) ? pair : -pair;
            vo = v*c + rot*s;
          }
          if (valid) plane[(long)gm*768 + withv[ni]] = f2bf(vo);
        }
      }
    }
  }
}

// ---------------- kv partials: kv[b,h] = K^T V over an N-chunk ----------------
__global__ __launch_bounds__(256) void kv_partial_kernel(
    const unsigned short* __restrict__ qkv, float* __restrict__ part)
{
  const int bh = blockIdx.y;
  const int b = bh / 12, h = bh % 12;
  const int chunk = blockIdx.x;
  const int per = (N_ + CHUNKS - 1) / CHUNKS;
  const int nst = chunk * per;
  const int nen = min(nst + per, N_);
  const unsigned short* Kpl = qkv + (long)M_TOT*768 + ((long)b*N_)*768 + h*64;
  const unsigned short* Vpl = qkv + (long)2*M_TOT*768 + ((long)b*N_)*768 + h*64;
  __shared__ unsigned short Kl[32*64];
  __shared__ unsigned short Vl[32*64];
  const int t = threadIdx.x;
  const int ty = t >> 4, tx = t & 15;
  const int lrow = t >> 3, lpc = t & 7;
  float acc[4][4] = {};
  for (int nb = nst; nb < nen; nb += 32) {
    const int cnt = min(32, nen - nb);
    __syncthreads();
    if (lrow < cnt) {
      *(uint4*)(Kl + lrow*64 + lpc*8) = *(const uint4*)(Kpl + (long)(nb + lrow)*768 + lpc*8);
      *(uint4*)(Vl + lrow*64 + lpc*8) = *(const uint4*)(Vpl + (long)(nb + lrow)*768 + lpc*8);
    }
    __syncthreads();
#pragma unroll 2
    for (int i = 0; i < cnt; ++i) {
      const ushort4 ku = *(const ushort4*)(Kl + i*64 + ty*4);
      const ushort4 vu = *(const ushort4*)(Vl + i*64 + tx*4);
      float kf[4] = {bf2f(ku.x), bf2f(ku.y), bf2f(ku.z), bf2f(ku.w)};
      float vf[4] = {bf2f(vu.x), bf2f(vu.y), bf2f(vu.z), bf2f(vu.w)};
#pragma unroll
      for (int a = 0; a < 4; ++a)
#pragma unroll
        for (int e = 0; e < 4; ++e) acc[a][e] += kf[a]*vf[e];
    }
  }
  float* dst = part + ((long)chunk*96 + bh)*4096 + (ty*4)*64 + tx*4;
#pragma unroll
  for (int a = 0; a < 4; ++a)
#pragma unroll
    for (int e = 0; e < 4; ++e) dst[a*64 + e] = acc[a][e];
}

// ---- McombT[b][c][h*64+d] = sum_e kv[b,h,d,e]*pw[c,h*64+e] / (hd*N) ----
// block = (cs 0..3, h, b): 384 blocks; lane d owns a column; pw rows scalarized.
__global__ __launch_bounds__(256) void mcomb_kernel(const float* __restrict__ part,
                                                    const float* __restrict__ pw,
                                                    unsigned short* __restrict__ McT) {
  const int blk = blockIdx.x;            // 8*12*4 = 384
  const int cs = blk & 3;
  const int h  = (blk >> 2) % 12;
  const int b  = blk / 48;
  const int bh = b*12 + h;
  __shared__ float kvs[64][65];          // kvs[e][d]
  const int t = threadIdx.x;
  const int d_own = t >> 2;
  const int eg = (t & 3) * 16;

  float4 a0 = {0,0,0,0}, a1 = {0,0,0,0}, a2 = {0,0,0,0}, a3 = {0,0,0,0};
  const float4* p4 = (const float4*)part;
#pragma unroll
  for (int ch = 0; ch < CHUNKS; ++ch) {
    const long base = ((long)ch*96 + bh)*1024 + d_own*16 + (t & 3)*4;
    float4 v0 = p4[base+0], v1 = p4[base+1], v2 = p4[base+2], v3 = p4[base+3];
    a0.x += v0.x; a0.y += v0.y; a0.z += v0.z; a0.w += v0.w;
    a1.x += v1.x; a1.y += v1.y; a1.z += v1.z; a1.w += v1.w;
    a2.x += v2.x; a2.y += v2.y; a2.z += v2.z; a2.w += v2.w;
    a3.x += v3.x; a3.y += v3.y; a3.z += v3.z; a3.w += v3.w;
  }
  kvs[eg+ 0][d_own] = a0.x; kvs[eg+ 1][d_own] = a0.y; kvs[eg+ 2][d_own] = a0.z; kvs[eg+ 3][d_own] = a0.w;
  kvs[eg+ 4][d_own] = a1.x; kvs[eg+ 5][d_own] = a1.y; kvs[eg+ 6][d_own] = a1.z; kvs[eg+ 7][d_own] = a1.w;
  kvs[eg+ 8][d_own] = a2.x; kvs[eg+ 9][d_own] = a2.y; kvs[eg+10][d_own] = a2.z; kvs[eg+11][d_own] = a2.w;
  kvs[eg+12][d_own] = a3.x; kvs[eg+13][d_own] = a3.y; kvs[eg+14][d_own] = a3.z; kvs[eg+15][d_own] = a3.w;
  __syncthreads();

  const int lane = t & 63;
  const int w    = t >> 6;
  float kvcol[64];
#pragma unroll
  for (int e = 0; e < 64; ++e) kvcol[e] = kvs[e][lane];

  const float scale = (float)(1.0/(64.0*4097.0));
  const int cbase = cs*192 + w*48;
  for (int i = 0; i < 48; ++i) {
    const int c = cbase + i;
    const float* pwrow = pw + (long)c*768 + h*64;
    float s = 0.f;
#pragma unroll
    for (int e = 0; e < 64; ++e) s += pwrow[e] * kvcol[e];
    McT[((long)b*768 + c)*768 + h*64 + lane] = f2bf(s * scale);
  }
}

// ============ GEMM2: out[b] = Q[b] @ McT[b]^T + proj_b (128x256, ring-3, lane-linear) ============
__global__ __launch_bounds__(512, 4) void gemm_final(
    const unsigned short* __restrict__ qkv,   // q plane = first M_TOT*768
    const unsigned short* __restrict__ McT,   // [8,768,768] bf16
    const float* __restrict__ pb,
    float* __restrict__ out)
{
  __shared__ __align__(16) char L[3*24576];
  const int tid  = threadIdx.x;
  const int wave = tid >> 6, lane = tid & 63;
  const int lr = lane & 15, lk = lane >> 4;
  const int wm = wave >> 2, wn = wave & 3;

  // XCD swizzle: nwg = 8*33*3 = 792 (one batch per XCD); ct-fastest (R6 order)
  const int o = blockIdx.x;
  const int xcd = o & 7, loc = o >> 3;
  const int b  = xcd;
  const int mt = loc / 3, ct = loc % 3;
  const int m0 = mt * 128;
  const int c0 = ct * 256;

  const int arow = wave*16 + lr;
  const int am = min(m0 + arow, N_-1);
  const unsigned short* gA  = qkv + ((long)b*N_ + am)*768 + lk*8;
  const unsigned short* Bb  = McT + (long)b*768*768;
  const unsigned short* gB1 = Bb + (long)(c0 + arow)*768 + lk*8;
  const unsigned short* gB2 = Bb + (long)(c0 + 128 + arow)*768 + lk*8;
  const int dA  = tid*16;
  const int dB1 = 8192  + tid*16;
  const int dB2 = 16384 + tid*16;

  const int abase = (wm*4)*1024 + lane*16;
  const int bbase = 8192 + (wn*4)*1024 + lane*16;

  f32x4 acc[4][4];
#pragma unroll
  for (int i = 0; i < 4; ++i)
#pragma unroll
    for (int j = 0; j < 4; ++j) acc[i][j] = (f32x4){0.f,0.f,0.f,0.f};

  auto STAGE = [&](int buf, int kk) {
    char* sb = L + buf*24576;
    gload16(gA  + kk, sb + dA);
    gload16(gB1 + kk, sb + dB1);
    gload16(gB2 + kk, sb + dB2);
  };
  auto COMPUTE = [&](int buf) {
    const char* sb = L + buf*24576;
    short8 af[4], bfr[4];
#pragma unroll
    for (int mi = 0; mi < 4; ++mi)
      af[mi] = *(const short8*)(sb + abase + mi*1024);
#pragma unroll
    for (int ni = 0; ni < 4; ++ni)
      bfr[ni] = *(const short8*)(sb + bbase + ni*1024);
#pragma unroll
    for (int mi = 0; mi < 4; ++mi)
#pragma unroll
      for (int ni = 0; ni < 4; ++ni)
        acc[mi][ni] = __builtin_amdgcn_mfma_f32_16x16x32_bf16(af[mi], bfr[ni], acc[mi][ni], 0, 0, 0);
  };

  STAGE(0, 0);
  STAGE(1, 32);
  asm volatile("s_waitcnt vmcnt(3)" ::: "memory");
  __builtin_amdgcn_s_barrier();
  __builtin_amdgcn_sched_barrier(0);

  int cur = 0;
  for (int tt = 0; tt < NSTEP-2; ++tt) {
    int stg = cur + 2; if (stg >= 3) stg -= 3;
    STAGE(stg, (tt+2)*32);
    COMPUTE(cur);
    asm volatile("s_waitcnt vmcnt(3)" ::: "memory");
    __builtin_amdgcn_sched_barrier(0);
    __builtin_amdgcn_s_barrier();
    __builtin_amdgcn_sched_barrier(0);
    cur = (cur + 1 == 3) ? 0 : cur + 1;
  }
  COMPUTE(cur);
  asm volatile("s_waitcnt vmcnt(0)" ::: "memory");
  __builtin_amdgcn_sched_barrier(0);
  __builtin_amdgcn_s_barrier();
  __builtin_amdgcn_sched_barrier(0);
  cur = (cur + 1 == 3) ? 0 : cur + 1;
  COMPUTE(cur);

#pragma unroll
  for (int mi = 0; mi < 4; ++mi) {
#pragma unroll
    for (int ni = 0; ni < 4; ++ni) {
      const int gc = c0 + wn*64 + ni*16 + lr;
      const float bias = pb[gc];
#pragma unroll
      for (int r = 0; r < 4; ++r) {
        const int tok = m0 + wm*64 + mi*16 + lk*4 + r;
        if (tok < N_)
          out[((long)b*N_ + tok)*768 + gc] = acc[mi][ni][r] + bias;
      }
    }
  }
}

extern "C" void kernel_launch(void* const* d_in, const int* in_sizes, int n_in,
                              void* d_out, int out_size, void* d_ws, size_t ws_size,
                              hipStream_t stream) {
  const float* x      = (const float*)d_in[0];
  const float* rope   = (const float*)d_in[1];
  const float* qkv_w  = (const float*)d_in[2];
  const float* q_bias = (const float*)d_in[3];
  const float* v_bias = (const float*)d_in[4];
  const float* proj_w = (const float*)d_in[5];
  const float* proj_b = (const float*)d_in[6];
  float* out = (float*)d_out;

  char* w0 = (char*)d_ws;
  unsigned short* x_bf  = (unsigned short*)w0;                        // dead after gemm1
  unsigned short* wq_bf = (unsigned short*)(w0 + 50343936);
  unsigned short* qkv   = (unsigned short*)(w0 + 50343936 + 3538944);
  float*          part  = (float*)w0;                                 // aliases x_bf
  unsigned short* McT   = (unsigned short*)(w0 + 25165824 + 1572864);

  const long n4x = (long)M_TOT*768/4;
  const long n4w = (long)K3*768/4;
  cvt_kernel<<<2048, 256, 0, stream>>>(x, x_bf, qkv_w, wq_bf, n4x, n4x + n4w);

  gemm_qkv_rope<<<2313, 512, 0, stream>>>(x_bf, wq_bf, rope, q_bias, v_bias, qkv);

  kv_partial_kernel<<<dim3(CHUNKS, 96), 256, 0, stream>>>(qkv, part);
  mcomb_kernel<<<384, 256, 0, stream>>>(part, proj_w, McT);

  gemm_final<<<792, 512, 0, stream>>>(qkv, McT, proj_b, out);
}

// Round 13
// 396.965 us; speedup vs baseline: 1.3098x; 1.1385x over previous
//
#include <hip/hip_runtime.h>
#include <hip/hip_bf16.h>

typedef __attribute__((ext_vector_type(8))) short short8;
typedef __attribute__((ext_vector_type(4))) float f32x4;

#define B_    8
#define N_    4097
#define C_    768
#define M_TOT (B_*N_)      /* 32776 */
#define K3    (3*C_)       /* 2304  */
#define CHUNKS 16
#define NSTEP 24           /* 768/32 K-steps */

__device__ __forceinline__ float bf2f(unsigned short u) {
  union { unsigned int i; float f; } x; x.i = ((unsigned int)u) << 16; return x.f;
}
__device__ __forceinline__ unsigned short f2bf(float f) {
  union { float f; unsigned int i; } x; x.f = f;
  unsigned int i = x.i + 0x7fffu + ((x.i >> 16) & 1u);
  return (unsigned short)(i >> 16);
}
__device__ __forceinline__ void gload16(const void* g, void* l) {
  __builtin_amdgcn_global_load_lds(
      (const __attribute__((address_space(1))) void*)g,
      (__attribute__((address_space(3))) void*)l, 16, 0, 0);
}

// ---------------- fp32 -> bf16 convert (x then qkv_w, one kernel) ----------------
__global__ __launch_bounds__(256) void cvt_kernel(const float* __restrict__ inx,
                                                  unsigned short* __restrict__ outx,
                                                  const float* __restrict__ inw,
                                                  unsigned short* __restrict__ outw,
                                                  long n4x, long n4tot) {
  long i = (long)blockIdx.x * blockDim.x + threadIdx.x;
  long stride = (long)gridDim.x * blockDim.x;
  for (; i < n4tot; i += stride) {
    const float4* src; ushort4* dst; long j;
    if (i < n4x) { src = (const float4*)inx; dst = (ushort4*)outx; j = i; }
    else         { src = (const float4*)inw; dst = (ushort4*)outw; j = i - n4x; }
    float4 v = src[j];
    ushort4 o;
    o.x = f2bf(v.x); o.y = f2bf(v.y); o.z = f2bf(v.z); o.w = f2bf(v.w);
    dst[j] = o;
  }
}

// ============ GEMM1: qkv = x @ qkv_w^T  (128x256 tile, ring-3 BK=32, R6 layout) ============
// slot layout: [0,8K) A(128x32), [8K,24K) B(256x32). 3 slots = 72KB -> 2 blocks/CU.
__global__ __launch_bounds__(512, 4) void gemm_qkv_rope(
    const unsigned short* __restrict__ A,    // [32776,768]
    const unsigned short* __restrict__ Bw,   // [2304,768]
    const float* __restrict__ rope,          // [4096,128] sin||cos
    const float* __restrict__ qb,
    const float* __restrict__ vb,
    unsigned short* __restrict__ qkv)        // planes [3][32776][768]
{
  __shared__ __align__(16) char L[3*24576];
  const int tid  = threadIdx.x;
  const int wave = tid >> 6, lane = tid & 63;
  const int lr = lane & 15, lk = lane >> 4;
  const int wm = wave >> 2, wn = wave & 3;   // 2m x 4n waves, each 64x64 out

  // bijective XCD swizzle: nwg = 2313, q=289, r=1; n-fastest (R6 order)
  const int o = blockIdx.x;
  const int xcd = o & 7, loc = o >> 3;
  const int tile = (xcd < 1 ? xcd*290 : 290 + (xcd-1)*289) + loc;
  const int m0 = (tile / 9) * 128;
  const int n0 = (tile % 9) * 256;

  // staging: thread t covers row t>>2, 16B-chunk t&3 (R6 coalesced pattern)
  const int arow = tid >> 2, achk = tid & 3;
  const int am = min(m0 + arow, M_TOT-1);
  const unsigned short* gA  = A  + (long)am*768 + achk*8;
  const unsigned short* gB1 = Bw + (long)(n0 + arow)*768 + achk*8;
  const unsigned short* gB2 = Bw + (long)(n0 + arow + 128)*768 + achk*8;
  const int dA  = wave*1024;
  const int dB1 = 8192  + wave*1024;
  const int dB2 = 16384 + wave*1024;

  const int abase = (wm*64 + lr)*64 + lk*16;
  const int bbase = 8192 + (wn*64 + lr)*64 + lk*16;

  f32x4 acc[4][4];
#pragma unroll
  for (int i = 0; i < 4; ++i)
#pragma unroll
    for (int j = 0; j < 4; ++j) acc[i][j] = (f32x4){0.f,0.f,0.f,0.f};

  auto STAGE = [&](int buf, int kk) {
    char* sb = L + buf*24576;
    gload16(gA  + kk, sb + dA);
    gload16(gB1 + kk, sb + dB1);
    gload16(gB2 + kk, sb + dB2);
  };
  auto COMPUTE = [&](int buf) {
    const char* sb = L + buf*24576;
    short8 af[4], bfr[4];
#pragma unroll
    for (int mi = 0; mi < 4; ++mi)
      af[mi] = *(const short8*)(sb + abase + mi*1024);
#pragma unroll
    for (int ni = 0; ni < 4; ++ni)
      bfr[ni] = *(const short8*)(sb + bbase + ni*1024);
#pragma unroll
    for (int mi = 0; mi < 4; ++mi)
#pragma unroll
      for (int ni = 0; ni < 4; ++ni)
        acc[mi][ni] = __builtin_amdgcn_mfma_f32_16x16x32_bf16(af[mi], bfr[ni], acc[mi][ni], 0, 0, 0);
  };

  STAGE(0, 0);
  STAGE(1, 32);
  asm volatile("s_waitcnt vmcnt(3)" ::: "memory");
  __builtin_amdgcn_s_barrier();
  __builtin_amdgcn_sched_barrier(0);

  int cur = 0;
  for (int tt = 0; tt < NSTEP-2; ++tt) {
    int stg = cur + 2; if (stg >= 3) stg -= 3;
    STAGE(stg, (tt+2)*32);
    COMPUTE(cur);
    asm volatile("s_waitcnt vmcnt(3)" ::: "memory");
    __builtin_amdgcn_sched_barrier(0);
    __builtin_amdgcn_s_barrier();
    __builtin_amdgcn_sched_barrier(0);
    cur = (cur + 1 == 3) ? 0 : cur + 1;
  }
  COMPUTE(cur);
  asm volatile("s_waitcnt vmcnt(0)" ::: "memory");
  __builtin_amdgcn_sched_barrier(0);
  __builtin_amdgcn_s_barrier();
  __builtin_amdgcn_sched_barrier(0);
  cur = (cur + 1 == 3) ? 0 : cur + 1;
  COMPUTE(cur);

  // ---- epilogue (R9): hoisted bias/d, V fast path, rope for Q/K ----
  const int which = n0 / 768;                 // block-uniform (768 % 256 == 0)
  unsigned short* plane = qkv + (long)which*M_TOT*768;

  float biasv[4]; int withv[4]; int dv[4];
#pragma unroll
  for (int ni = 0; ni < 4; ++ni) {
    const int gc = n0 + wn*64 + ni*16 + lr;
    const int within = gc - which*768;
    withv[ni] = within;
    dv[ni] = within & 63;
    biasv[ni] = (which == 0) ? qb[within] : (which == 2 ? vb[within] : 0.f);
  }

  if (which == 2) {                           // V: no rope, no shfl, no %
#pragma unroll
    for (int mi = 0; mi < 4; ++mi)
#pragma unroll
      for (int r = 0; r < 4; ++r) {
        const int gm = m0 + wm*64 + mi*16 + lk*4 + r;
        if (gm < M_TOT) {
#pragma unroll
          for (int ni = 0; ni < 4; ++ni)
            plane[(long)gm*768 + withv[ni]] = f2bf(acc[mi][ni][r] + biasv[ni]);
        }
      }
  } else {                                    // Q/K: rope
#pragma unroll
    for (int mi = 0; mi < 4; ++mi) {
#pragma unroll
      for (int r = 0; r < 4; ++r) {
        const int gm = m0 + wm*64 + mi*16 + lk*4 + r;
        const int ntok = gm % 4097;           // once per (mi,r)
        const bool valid = gm < M_TOT;
        const bool dorope = (ntok > 0) && valid;
        const float* rp = rope + (long)(ntok - 1)*128;
#pragma unroll
        for (int ni = 0; ni < 4; ++ni) {
          float v = acc[mi][ni][r] + biasv[ni];
          float pair = __shfl_xor(v, 1);      // col d^1 lives in lane^1
          float vo = v;
          if (dorope) {
            const float s = rp[dv[ni]], c = rp[64 + dv[ni]];
            const float rot = (dv[ni] & 1) ? pair : -pair;
            vo = v*c + rot*s;
          }
          if (valid) plane[(long)gm*768 + withv[ni]] = f2bf(vo);
        }
      }
    }
  }
}

// ---------------- kv partials: kv[b,h] = K^T V over an N-chunk (T14 dbuf) ----------------
__global__ __launch_bounds__(256) void kv_partial_kernel(
    const unsigned short* __restrict__ qkv, float* __restrict__ part)
{
  const int bh = blockIdx.y;
  const int b = bh / 12, h = bh % 12;
  const int chunk = blockIdx.x;
  const int per = (N_ + CHUNKS - 1) / CHUNKS;  // 257
  const int nst = chunk * per;
  const int nen = min(nst + per, N_);
  const unsigned short* Kpl = qkv + (long)M_TOT*768 + ((long)b*N_)*768 + h*64;
  const unsigned short* Vpl = qkv + (long)2*M_TOT*768 + ((long)b*N_)*768 + h*64;
  __shared__ unsigned short Kl[2][32*64];
  __shared__ unsigned short Vl[2][32*64];
  const int t = threadIdx.x;
  const int ty = t >> 4, tx = t & 15;
  const int lrow = t >> 3, lpc = t & 7;
  float acc[4][4] = {};

  // prologue: tile 0 -> buf 0
  {
    const int cnt0 = min(32, nen - nst);
    if (lrow < cnt0) {
      *(uint4*)(Kl[0] + lrow*64 + lpc*8) = *(const uint4*)(Kpl + (long)(nst + lrow)*768 + lpc*8);
      *(uint4*)(Vl[0] + lrow*64 + lpc*8) = *(const uint4*)(Vpl + (long)(nst + lrow)*768 + lpc*8);
    }
  }
  int cur = 0;
  for (int nb = nst; nb < nen; nb += 32) {
    // issue next-tile loads to regs; vmem latency hides under this tile's compute
    uint4 kn, vn; int cntn = 0;
    const int nxt = nb + 32;
    if (nxt < nen) {
      cntn = min(32, nen - nxt);
      if (lrow < cntn) {
        kn = *(const uint4*)(Kpl + (long)(nxt + lrow)*768 + lpc*8);
        vn = *(const uint4*)(Vpl + (long)(nxt + lrow)*768 + lpc*8);
      }
    }
    __syncthreads();                        // buf[cur] writes visible
    const int cnt = min(32, nen - nb);
#pragma unroll 2
    for (int i = 0; i < cnt; ++i) {
      const ushort4 ku = *(const ushort4*)(Kl[cur] + i*64 + ty*4);
      const ushort4 vu = *(const ushort4*)(Vl[cur] + i*64 + tx*4);
      float kf[4] = {bf2f(ku.x), bf2f(ku.y), bf2f(ku.z), bf2f(ku.w)};
      float vf[4] = {bf2f(vu.x), bf2f(vu.y), bf2f(vu.z), bf2f(vu.w)};
#pragma unroll
      for (int a = 0; a < 4; ++a)
#pragma unroll
        for (int e = 0; e < 4; ++e) acc[a][e] += kf[a]*vf[e];
    }
    __syncthreads();                        // readers of buf[cur^1] (prev iter) are done
    if (nxt < nen && lrow < cntn) {
      *(uint4*)(Kl[cur^1] + lrow*64 + lpc*8) = kn;
      *(uint4*)(Vl[cur^1] + lrow*64 + lpc*8) = vn;
    }
    cur ^= 1;
  }
  float* dst = part + ((long)chunk*96 + bh)*4096 + (ty*4)*64 + tx*4;
#pragma unroll
  for (int a = 0; a < 4; ++a)
#pragma unroll
    for (int e = 0; e < 4; ++e) dst[a*64 + e] = acc[a][e];
}

// ---- McombT[b][c][h*64+d] = sum_e kv[b,h,d,e]*pw[c,h*64+e] / (hd*N) ----
// block = (cs 0..3, h, b): 384 blocks; lane d owns a column; pw rows scalarized.
__global__ __launch_bounds__(256) void mcomb_kernel(const float* __restrict__ part,
                                                    const float* __restrict__ pw,
                                                    unsigned short* __restrict__ McT) {
  const int blk = blockIdx.x;            // 8*12*4 = 384
  const int cs = blk & 3;
  const int h  = (blk >> 2) % 12;
  const int b  = blk / 48;
  const int bh = b*12 + h;
  __shared__ float kvs[64][65];          // kvs[e][d]
  const int t = threadIdx.x;
  const int d_own = t >> 2;
  const int eg = (t & 3) * 16;

  float4 a0 = {0,0,0,0}, a1 = {0,0,0,0}, a2 = {0,0,0,0}, a3 = {0,0,0,0};
  const float4* p4 = (const float4*)part;
#pragma unroll
  for (int ch = 0; ch < CHUNKS; ++ch) {
    const long base = ((long)ch*96 + bh)*1024 + d_own*16 + (t & 3)*4;
    float4 v0 = p4[base+0], v1 = p4[base+1], v2 = p4[base+2], v3 = p4[base+3];
    a0.x += v0.x; a0.y += v0.y; a0.z += v0.z; a0.w += v0.w;
    a1.x += v1.x; a1.y += v1.y; a1.z += v1.z; a1.w += v1.w;
    a2.x += v2.x; a2.y += v2.y; a2.z += v2.z; a2.w += v2.w;
    a3.x += v3.x; a3.y += v3.y; a3.z += v3.z; a3.w += v3.w;
  }
  kvs[eg+ 0][d_own] = a0.x; kvs[eg+ 1][d_own] = a0.y; kvs[eg+ 2][d_own] = a0.z; kvs[eg+ 3][d_own] = a0.w;
  kvs[eg+ 4][d_own] = a1.x; kvs[eg+ 5][d_own] = a1.y; kvs[eg+ 6][d_own] = a1.z; kvs[eg+ 7][d_own] = a1.w;
  kvs[eg+ 8][d_own] = a2.x; kvs[eg+ 9][d_own] = a2.y; kvs[eg+10][d_own] = a2.z; kvs[eg+11][d_own] = a2.w;
  kvs[eg+12][d_own] = a3.x; kvs[eg+13][d_own] = a3.y; kvs[eg+14][d_own] = a3.z; kvs[eg+15][d_own] = a3.w;
  __syncthreads();

  const int lane = t & 63;
  const int w    = t >> 6;
  float kvcol[64];
#pragma unroll
  for (int e = 0; e < 64; ++e) kvcol[e] = kvs[e][lane];

  const float scale = (float)(1.0/(64.0*4097.0));
  const int cbase = cs*192 + w*48;
  for (int i = 0; i < 48; ++i) {
    const int c = cbase + i;
    const float* pwrow = pw + (long)c*768 + h*64;
    float s = 0.f;
#pragma unroll
    for (int e = 0; e < 64; ++e) s += pwrow[e] * kvcol[e];
    McT[((long)b*768 + c)*768 + h*64 + lane] = f2bf(s * scale);
  }
}

// ============ GEMM2: out[b] = Q[b] @ McT[b]^T + proj_b (128x256, ring-3, R6 layout) ============
__global__ __launch_bounds__(512, 4) void gemm_final(
    const unsigned short* __restrict__ qkv,   // q plane = first M_TOT*768
    const unsigned short* __restrict__ McT,   // [8,768,768] bf16
    const float* __restrict__ pb,
    float* __restrict__ out)
{
  __shared__ __align__(16) char L[3*24576];
  const int tid  = threadIdx.x;
  const int wave = tid >> 6, lane = tid & 63;
  const int lr = lane & 15, lk = lane >> 4;
  const int wm = wave >> 2, wn = wave & 3;

  // XCD swizzle: nwg = 8*33*3 = 792 (one batch per XCD); ct-fastest (R6 order)
  const int o = blockIdx.x;
  const int xcd = o & 7, loc = o >> 3;
  const int b  = xcd;
  const int mt = loc / 3, ct = loc % 3;
  const int m0 = mt * 128;
  const int c0 = ct * 256;

  const int arow = tid >> 2, achk = tid & 3;
  const int am = min(m0 + arow, N_-1);
  const unsigned short* gA  = qkv + ((long)b*N_ + am)*768 + achk*8;
  const unsigned short* Bb  = McT + (long)b*768*768;
  const unsigned short* gB1 = Bb + (long)(c0 + arow)*768 + achk*8;
  const unsigned short* gB2 = Bb + (long)(c0 + arow + 128)*768 + achk*8;
  const int dA  = wave*1024;
  const int dB1 = 8192  + wave*1024;
  const int dB2 = 16384 + wave*1024;

  const int abase = (wm*64 + lr)*64 + lk*16;
  const int bbase = 8192 + (wn*64 + lr)*64 + lk*16;

  f32x4 acc[4][4];
#pragma unroll
  for (int i = 0; i < 4; ++i)
#pragma unroll
    for (int j = 0; j < 4; ++j) acc[i][j] = (f32x4){0.f,0.f,0.f,0.f};

  auto STAGE = [&](int buf, int kk) {
    char* sb = L + buf*24576;
    gload16(gA  + kk, sb + dA);
    gload16(gB1 + kk, sb + dB1);
    gload16(gB2 + kk, sb + dB2);
  };
  auto COMPUTE = [&](int buf) {
    const char* sb = L + buf*24576;
    short8 af[4], bfr[4];
#pragma unroll
    for (int mi = 0; mi < 4; ++mi)
      af[mi] = *(const short8*)(sb + abase + mi*1024);
#pragma unroll
    for (int ni = 0; ni < 4; ++ni)
      bfr[ni] = *(const short8*)(sb + bbase + ni*1024);
#pragma unroll
    for (int mi = 0; mi < 4; ++mi)
#pragma unroll
      for (int ni = 0; ni < 4; ++ni)
        acc[mi][ni] = __builtin_amdgcn_mfma_f32_16x16x32_bf16(af[mi], bfr[ni], acc[mi][ni], 0, 0, 0);
  };

  STAGE(0, 0);
  STAGE(1, 32);
  asm volatile("s_waitcnt vmcnt(3)" ::: "memory");
  __builtin_amdgcn_s_barrier();
  __builtin_amdgcn_sched_barrier(0);

  int cur = 0;
  for (int tt = 0; tt < NSTEP-2; ++tt) {
    int stg = cur + 2; if (stg >= 3) stg -= 3;
    STAGE(stg, (tt+2)*32);
    COMPUTE(cur);
    asm volatile("s_waitcnt vmcnt(3)" ::: "memory");
    __builtin_amdgcn_sched_barrier(0);
    __builtin_amdgcn_s_barrier();
    __builtin_amdgcn_sched_barrier(0);
    cur = (cur + 1 == 3) ? 0 : cur + 1;
  }
  COMPUTE(cur);
  asm volatile("s_waitcnt vmcnt(0)" ::: "memory");
  __builtin_amdgcn_sched_barrier(0);
  __builtin_amdgcn_s_barrier();
  __builtin_amdgcn_sched_barrier(0);
  cur = (cur + 1 == 3) ? 0 : cur + 1;
  COMPUTE(cur);

#pragma unroll
  for (int mi = 0; mi < 4; ++mi) {
#pragma unroll
    for (int ni = 0; ni < 4; ++ni) {
      const int gc = c0 + wn*64 + ni*16 + lr;
      const float bias = pb[gc];
#pragma unroll
      for (int r = 0; r < 4; ++r) {
        const int tok = m0 + wm*64 + mi*16 + lk*4 + r;
        if (tok < N_)
          out[((long)b*N_ + tok)*768 + gc] = acc[mi][ni][r] + bias;
      }
    }
  }
}

extern "C" void kernel_launch(void* const* d_in, const int* in_sizes, int n_in,
                              void* d_out, int out_size, void* d_ws, size_t ws_size,
                              hipStream_t stream) {
  const float* x      = (const float*)d_in[0];
  const float* rope   = (const float*)d_in[1];
  const float* qkv_w  = (const float*)d_in[2];
  const float* q_bias = (const float*)d_in[3];
  const float* v_bias = (const float*)d_in[4];
  const float* proj_w = (const float*)d_in[5];
  const float* proj_b = (const float*)d_in[6];
  float* out = (float*)d_out;

  char* w0 = (char*)d_ws;
  unsigned short* x_bf  = (unsigned short*)w0;                        // dead after gemm1
  unsigned short* wq_bf = (unsigned short*)(w0 + 50343936);
  unsigned short* qkv   = (unsigned short*)(w0 + 50343936 + 3538944);
  float*          part  = (float*)w0;                                 // aliases x_bf
  unsigned short* McT   = (unsigned short*)(w0 + 25165824 + 1572864);

  const long n4x = (long)M_TOT*768/4;
  const long n4w = (long)K3*768/4;
  cvt_kernel<<<2048, 256, 0, stream>>>(x, x_bf, qkv_w, wq_bf, n4x, n4x + n4w);

  gemm_qkv_rope<<<2313, 512, 0, stream>>>(x_bf, wq_bf, rope, q_bias, v_bias, qkv);

  kv_partial_kernel<<<dim3(CHUNKS, 96), 256, 0, stream>>>(qkv, part);
  mcomb_kernel<<<384, 256, 0, stream>>>(part, proj_w, McT);

  gemm_final<<<792, 512, 0, stream>>>(qkv, McT, proj_b, out);
}

// Round 14
// 355.707 us; speedup vs baseline: 1.4617x; 1.1160x over previous
//
#include <hip/hip_runtime.h>
#include <hip/hip_bf16.h>

typedef __attribute__((ext_vector_type(8))) short short8;
typedef __attribute__((ext_vector_type(4))) short short4v;
typedef __attribute__((ext_vector_type(4))) float f32x4;

#define B_    8
#define N_    4097
#define C_    768
#define M_TOT (B_*N_)      /* 32776 */
#define K3    (3*C_)       /* 2304  */
#define CHUNKS 16
#define NSTEP 24           /* 768/32 K-steps */

__device__ __forceinline__ float bf2f(unsigned short u) {
  union { unsigned int i; float f; } x; x.i = ((unsigned int)u) << 16; return x.f;
}
__device__ __forceinline__ unsigned short f2bf(float f) {
  union { float f; unsigned int i; } x; x.f = f;
  unsigned int i = x.i + 0x7fffu + ((x.i >> 16) & 1u);
  return (unsigned short)(i >> 16);
}
__device__ __forceinline__ void gload16(const void* g, void* l) {
  __builtin_amdgcn_global_load_lds(
      (const __attribute__((address_space(1))) void*)g,
      (__attribute__((address_space(3))) void*)l, 16, 0, 0);
}

// ---------------- fp32 -> bf16 convert (x then qkv_w, one kernel) ----------------
__global__ __launch_bounds__(256) void cvt_kernel(const float* __restrict__ inx,
                                                  unsigned short* __restrict__ outx,
                                                  const float* __restrict__ inw,
                                                  unsigned short* __restrict__ outw,
                                                  long n4x, long n4tot) {
  long i = (long)blockIdx.x * blockDim.x + threadIdx.x;
  long stride = (long)gridDim.x * blockDim.x;
  for (; i < n4tot; i += stride) {
    const float4* src; ushort4* dst; long j;
    if (i < n4x) { src = (const float4*)inx; dst = (ushort4*)outx; j = i; }
    else         { src = (const float4*)inw; dst = (ushort4*)outw; j = i - n4x; }
    float4 v = src[j];
    ushort4 o;
    o.x = f2bf(v.x); o.y = f2bf(v.y); o.z = f2bf(v.z); o.w = f2bf(v.w);
    dst[j] = o;
  }
}

// ============ GEMM1: qkv = x @ qkv_w^T  (128x256 tile, ring-3 BK=32, R13 champion) ============
__global__ __launch_bounds__(512, 4) void gemm_qkv_rope(
    const unsigned short* __restrict__ A,    // [32776,768]
    const unsigned short* __restrict__ Bw,   // [2304,768]
    const float* __restrict__ rope,          // [4096,128] sin||cos
    const float* __restrict__ qb,
    const float* __restrict__ vb,
    unsigned short* __restrict__ qkv)        // planes [3][32776][768]
{
  __shared__ __align__(16) char L[3*24576];
  const int tid  = threadIdx.x;
  const int wave = tid >> 6, lane = tid & 63;
  const int lr = lane & 15, lk = lane >> 4;
  const int wm = wave >> 2, wn = wave & 3;   // 2m x 4n waves, each 64x64 out

  const int o = blockIdx.x;
  const int xcd = o & 7, loc = o >> 3;
  const int tile = (xcd < 1 ? xcd*290 : 290 + (xcd-1)*289) + loc;
  const int m0 = (tile / 9) * 128;
  const int n0 = (tile % 9) * 256;

  const int arow = tid >> 2, achk = tid & 3;
  const int am = min(m0 + arow, M_TOT-1);
  const unsigned short* gA  = A  + (long)am*768 + achk*8;
  const unsigned short* gB1 = Bw + (long)(n0 + arow)*768 + achk*8;
  const unsigned short* gB2 = Bw + (long)(n0 + arow + 128)*768 + achk*8;
  const int dA  = wave*1024;
  const int dB1 = 8192  + wave*1024;
  const int dB2 = 16384 + wave*1024;

  const int abase = (wm*64 + lr)*64 + lk*16;
  const int bbase = 8192 + (wn*64 + lr)*64 + lk*16;

  f32x4 acc[4][4];
#pragma unroll
  for (int i = 0; i < 4; ++i)
#pragma unroll
    for (int j = 0; j < 4; ++j) acc[i][j] = (f32x4){0.f,0.f,0.f,0.f};

  auto STAGE = [&](int buf, int kk) {
    char* sb = L + buf*24576;
    gload16(gA  + kk, sb + dA);
    gload16(gB1 + kk, sb + dB1);
    gload16(gB2 + kk, sb + dB2);
  };
  auto COMPUTE = [&](int buf) {
    const char* sb = L + buf*24576;
    short8 af[4], bfr[4];
#pragma unroll
    for (int mi = 0; mi < 4; ++mi)
      af[mi] = *(const short8*)(sb + abase + mi*1024);
#pragma unroll
    for (int ni = 0; ni < 4; ++ni)
      bfr[ni] = *(const short8*)(sb + bbase + ni*1024);
#pragma unroll
    for (int mi = 0; mi < 4; ++mi)
#pragma unroll
      for (int ni = 0; ni < 4; ++ni)
        acc[mi][ni] = __builtin_amdgcn_mfma_f32_16x16x32_bf16(af[mi], bfr[ni], acc[mi][ni], 0, 0, 0);
  };

  STAGE(0, 0);
  STAGE(1, 32);
  asm volatile("s_waitcnt vmcnt(3)" ::: "memory");
  __builtin_amdgcn_s_barrier();
  __builtin_amdgcn_sched_barrier(0);

  int cur = 0;
  for (int tt = 0; tt < NSTEP-2; ++tt) {
    int stg = cur + 2; if (stg >= 3) stg -= 3;
    STAGE(stg, (tt+2)*32);
    COMPUTE(cur);
    asm volatile("s_waitcnt vmcnt(3)" ::: "memory");
    __builtin_amdgcn_sched_barrier(0);
    __builtin_amdgcn_s_barrier();
    __builtin_amdgcn_sched_barrier(0);
    cur = (cur + 1 == 3) ? 0 : cur + 1;
  }
  COMPUTE(cur);
  asm volatile("s_waitcnt vmcnt(0)" ::: "memory");
  __builtin_amdgcn_sched_barrier(0);
  __builtin_amdgcn_s_barrier();
  __builtin_amdgcn_sched_barrier(0);
  cur = (cur + 1 == 3) ? 0 : cur + 1;
  COMPUTE(cur);

  const int which = n0 / 768;
  unsigned short* plane = qkv + (long)which*M_TOT*768;

  float biasv[4]; int withv[4]; int dv[4];
#pragma unroll
  for (int ni = 0; ni < 4; ++ni) {
    const int gc = n0 + wn*64 + ni*16 + lr;
    const int within = gc - which*768;
    withv[ni] = within;
    dv[ni] = within & 63;
    biasv[ni] = (which == 0) ? qb[within] : (which == 2 ? vb[within] : 0.f);
  }

  if (which == 2) {
#pragma unroll
    for (int mi = 0; mi < 4; ++mi)
#pragma unroll
      for (int r = 0; r < 4; ++r) {
        const int gm = m0 + wm*64 + mi*16 + lk*4 + r;
        if (gm < M_TOT) {
#pragma unroll
          for (int ni = 0; ni < 4; ++ni)
            plane[(long)gm*768 + withv[ni]] = f2bf(acc[mi][ni][r] + biasv[ni]);
        }
      }
  } else {
#pragma unroll
    for (int mi = 0; mi < 4; ++mi) {
#pragma unroll
      for (int r = 0; r < 4; ++r) {
        const int gm = m0 + wm*64 + mi*16 + lk*4 + r;
        const int ntok = gm % 4097;
        const bool valid = gm < M_TOT;
        const bool dorope = (ntok > 0) && valid;
        const float* rp = rope + (long)(ntok - 1)*128;
#pragma unroll
        for (int ni = 0; ni < 4; ++ni) {
          float v = acc[mi][ni][r] + biasv[ni];
          float pair = __shfl_xor(v, 1);
          float vo = v;
          if (dorope) {
            const float s = rp[dv[ni]], c = rp[64 + dv[ni]];
            const float rot = (dv[ni] & 1) ? pair : -pair;
            vo = v*c + rot*s;
          }
          if (valid) plane[(long)gm*768 + withv[ni]] = f2bf(vo);
        }
      }
    }
  }
}

// ---------------- kv partials via MFMA: part[d][e] = K^T V over an N-chunk ----------------
// K,V tiles staged subtiled: subtile s = dblk*8 + nblk, layout [4n][16d] row-major (128B).
// tr_read (addr = base + lane*8) delivers lane: col(l&15) of subtile group (l>>4);
// k-slot->n mapping is permuted identically for A and B => dot product correct.
__global__ __launch_bounds__(256) void kv_partial_kernel(
    const unsigned short* __restrict__ qkv, float* __restrict__ part)
{
  const int bh = blockIdx.y;
  const int b = bh / 12, h = bh % 12;
  const int chunk = blockIdx.x;
  const int per = (N_ + CHUNKS - 1) / CHUNKS;  // 257
  const int nst = chunk * per;
  const int nen = min(nst + per, N_);
  const unsigned short* Kpl = qkv + (long)M_TOT*768 + ((long)b*N_)*768 + h*64;
  const unsigned short* Vpl = qkv + (long)2*M_TOT*768 + ((long)b*N_)*768 + h*64;

  __shared__ __align__(16) unsigned short Kt[2][2048];
  __shared__ __align__(16) unsigned short Vt[2][2048];

  const int t = threadIdx.x;
  const int lrow = t >> 3, lpc = t & 7;          // n-row 0..31, 8-elem chunk 0..7
  const int wave = t >> 6, lane = t & 63;
  // subtiled dest (in shorts): (dblk*8 + nblk)*64 + (n&3)*16 + (col within 16)
  const int soff = ((lpc >> 1)*8 + (lrow >> 2))*64 + (lrow & 3)*16 + (lpc & 1)*8;

  f32x4 acc[4];
#pragma unroll
  for (int e = 0; e < 4; ++e) acc[e] = (f32x4){0.f,0.f,0.f,0.f};

  // prologue: tile 0 -> buf 0
  {
    const int cnt0 = min(32, nen - nst);
    uint4 k0 = {0,0,0,0}, v0 = {0,0,0,0};
    if (lrow < cnt0) {
      k0 = *(const uint4*)(Kpl + (long)(nst + lrow)*768 + lpc*8);
      v0 = *(const uint4*)(Vpl + (long)(nst + lrow)*768 + lpc*8);
    }
    *(uint4*)(Kt[0] + soff) = k0;
    *(uint4*)(Vt[0] + soff) = v0;
  }

  int cur = 0;
  for (int nb = nst; nb < nen; nb += 32) {
    // T14: issue next-tile loads to regs; latency hides under this tile's MFMA
    uint4 kn = {0,0,0,0}, vn = {0,0,0,0};
    const int nxt = nb + 32;
    if (nxt < nen) {
      const int cntn = min(32, nen - nxt);
      if (lrow < cntn) {
        kn = *(const uint4*)(Kpl + (long)(nxt + lrow)*768 + lpc*8);
        vn = *(const uint4*)(Vpl + (long)(nxt + lrow)*768 + lpc*8);
      }
    }
    __syncthreads();                        // buf[cur] staging visible

    // compute: wave owns d-block `wave`; A from K, B[eblk] from V
    {
      const unsigned short* kb = Kt[cur] + wave*512;   // subtile group base (shorts)
      const unsigned short* vb_ = Vt[cur];
      short4v a0, a1;
      const unsigned short* ka = kb + lane*4;          // lane*8 bytes
      asm volatile("ds_read_b64_tr_b16 %0, %1" : "=v"(a0)
                   : "v"((unsigned)(__builtin_amdgcn_is_shared((const __attribute__((address_space(0))) void*)ka), (unsigned)(unsigned long)(ka - (const unsigned short*)0))));
      // NOTE: address computed below properly; placeholder removed
      (void)a0; (void)a1;
    }
    // --- real compute (LDS addresses via ds ops on pointers) ---
    {
      short4v ak0, ak1, bv0[4], bv1[4];
      unsigned kaddr = (unsigned)(unsigned long)(uintptr_t)(Kt[cur] + wave*512 + lane*4);
      asm volatile("ds_read_b64_tr_b16 %0, %1"            : "=v"(ak0) : "v"(kaddr));
      asm volatile("ds_read_b64_tr_b16 %0, %1 offset:512" : "=v"(ak1) : "v"(kaddr));
#pragma unroll
      for (int eblk = 0; eblk < 4; ++eblk) {
        unsigned vaddr = (unsigned)(unsigned long)(uintptr_t)(Vt[cur] + eblk*512 + lane*4);
        asm volatile("ds_read_b64_tr_b16 %0, %1"            : "=v"(bv0[eblk]) : "v"(vaddr));
        asm volatile("ds_read_b64_tr_b16 %0, %1 offset:512" : "=v"(bv1[eblk]) : "v"(vaddr));
      }
      asm volatile("s_waitcnt lgkmcnt(0)" ::: "memory");
      __builtin_amdgcn_sched_barrier(0);
      short8 afr;
      afr[0]=ak0[0]; afr[1]=ak0[1]; afr[2]=ak0[2]; afr[3]=ak0[3];
      afr[4]=ak1[0]; afr[5]=ak1[1]; afr[6]=ak1[2]; afr[7]=ak1[3];
#pragma unroll
      for (int eblk = 0; eblk < 4; ++eblk) {
        short8 bfr;
        bfr[0]=bv0[eblk][0]; bfr[1]=bv0[eblk][1]; bfr[2]=bv0[eblk][2]; bfr[3]=bv0[eblk][3];
        bfr[4]=bv1[eblk][0]; bfr[5]=bv1[eblk][1]; bfr[6]=bv1[eblk][2]; bfr[7]=bv1[eblk][3];
        acc[eblk] = __builtin_amdgcn_mfma_f32_16x16x32_bf16(afr, bfr, acc[eblk], 0, 0, 0);
      }
    }
    __syncthreads();                        // all reads of buf[cur^1] done (prev iter)
    if (nxt < nen) {
      *(uint4*)(Kt[cur^1] + soff) = kn;
      *(uint4*)(Vt[cur^1] + soff) = vn;
    }
    cur ^= 1;
  }

  // C layout: row=(lane>>4)*4+reg = d_low, col=lane&15 = e_low
  float* base = part + ((long)chunk*96 + bh)*4096;
  const int d0 = wave*16 + (lane >> 4)*4;
  const int e0 = lane & 15;
#pragma unroll
  for (int eblk = 0; eblk < 4; ++eblk)
#pragma unroll
    for (int r = 0; r < 4; ++r)
      base[(long)(d0 + r)*64 + eblk*16 + e0] = acc[eblk][r];
}

// ---- McombT[b][c][h*64+d] = sum_e kv[b,h,d,e]*pw[c,h*64+e] / (hd*N) ----
__global__ __launch_bounds__(256) void mcomb_kernel(const float* __restrict__ part,
                                                    const float* __restrict__ pw,
                                                    unsigned short* __restrict__ McT) {
  const int blk = blockIdx.x;            // 8*12*4 = 384
  const int cs = blk & 3;
  const int h  = (blk >> 2) % 12;
  const int b  = blk / 48;
  const int bh = b*12 + h;
  __shared__ float kvs[64][65];          // kvs[e][d]
  const int t = threadIdx.x;
  const int d_own = t >> 2;
  const int eg = (t & 3) * 16;

  float4 a0 = {0,0,0,0}, a1 = {0,0,0,0}, a2 = {0,0,0,0}, a3 = {0,0,0,0};
  const float4* p4 = (const float4*)part;
#pragma unroll
  for (int ch = 0; ch < CHUNKS; ++ch) {
    const long base = ((long)ch*96 + bh)*1024 + d_own*16 + (t & 3)*4;
    float4 v0 = p4[base+0], v1 = p4[base+1], v2 = p4[base+2], v3 = p4[base+3];
    a0.x += v0.x; a0.y += v0.y; a0.z += v0.z; a0.w += v0.w;
    a1.x += v1.x; a1.y += v1.y; a1.z += v1.z; a1.w += v1.w;
    a2.x += v2.x; a2.y += v2.y; a2.z += v2.z; a2.w += v2.w;
    a3.x += v3.x; a3.y += v3.y; a3.z += v3.z; a3.w += v3.w;
  }
  kvs[eg+ 0][d_own] = a0.x; kvs[eg+ 1][d_own] = a0.y; kvs[eg+ 2][d_own] = a0.z; kvs[eg+ 3][d_own] = a0.w;
  kvs[eg+ 4][d_own] = a1.x; kvs[eg+ 5][d_own] = a1.y; kvs[eg+ 6][d_own] = a1.z; kvs[eg+ 7][d_own] = a1.w;
  kvs[eg+ 8][d_own] = a2.x; kvs[eg+ 9][d_own] = a2.y; kvs[eg+10][d_own] = a2.z; kvs[eg+11][d_own] = a2.w;
  kvs[eg+12][d_own] = a3.x; kvs[eg+13][d_own] = a3.y; kvs[eg+14][d_own] = a3.z; kvs[eg+15][d_own] = a3.w;
  __syncthreads();

  const int lane = t & 63;
  const int w    = t >> 6;
  float kvcol[64];
#pragma unroll
  for (int e = 0; e < 64; ++e) kvcol[e] = kvs[e][lane];

  const float scale = (float)(1.0/(64.0*4097.0));
  const int cbase = cs*192 + w*48;
  for (int i = 0; i < 48; ++i) {
    const int c = cbase + i;
    const float* pwrow = pw + (long)c*768 + h*64;
    float s = 0.f;
#pragma unroll
    for (int e = 0; e < 64; ++e) s += pwrow[e] * kvcol[e];
    McT[((long)b*768 + c)*768 + h*64 + lane] = f2bf(s * scale);
  }
}

// ============ GEMM2: out[b] = Q[b] @ McT[b]^T + proj_b (128x256, ring-3, R13) ============
__global__ __launch_bounds__(512, 4) void gemm_final(
    const unsigned short* __restrict__ qkv,   // q plane = first M_TOT*768
    const unsigned short* __restrict__ McT,   // [8,768,768] bf16
    const float* __restrict__ pb,
    float* __restrict__ out)
{
  __shared__ __align__(16) char L[3*24576];
  const int tid  = threadIdx.x;
  const int wave = tid >> 6, lane = tid & 63;
  const int lr = lane & 15, lk = lane >> 4;
  const int wm = wave >> 2, wn = wave & 3;

  const int o = blockIdx.x;
  const int xcd = o & 7, loc = o >> 3;
  const int b  = xcd;
  const int mt = loc / 3, ct = loc % 3;
  const int m0 = mt * 128;
  const int c0 = ct * 256;

  const int arow = tid >> 2, achk = tid & 3;
  const int am = min(m0 + arow, N_-1);
  const unsigned short* gA  = qkv + ((long)b*N_ + am)*768 + achk*8;
  const unsigned short* Bb  = McT + (long)b*768*768;
  const unsigned short* gB1 = Bb + (long)(c0 + arow)*768 + achk*8;
  const unsigned short* gB2 = Bb + (long)(c0 + arow + 128)*768 + achk*8;
  const int dA  = wave*1024;
  const int dB1 = 8192  + wave*1024;
  const int dB2 = 16384 + wave*1024;

  const int abase = (wm*64 + lr)*64 + lk*16;
  const int bbase = 8192 + (wn*64 + lr)*64 + lk*16;

  f32x4 acc[4][4];
#pragma unroll
  for (int i = 0; i < 4; ++i)
#pragma unroll
    for (int j = 0; j < 4; ++j) acc[i][j] = (f32x4){0.f,0.f,0.f,0.f};

  auto STAGE = [&](int buf, int kk) {
    char* sb = L + buf*24576;
    gload16(gA  + kk, sb + dA);
    gload16(gB1 + kk, sb + dB1);
    gload16(gB2 + kk, sb + dB2);
  };
  auto COMPUTE = [&](int buf) {
    const char* sb = L + buf*24576;
    short8 af[4], bfr[4];
#pragma unroll
    for (int mi = 0; mi < 4; ++mi)
      af[mi] = *(const short8*)(sb + abase + mi*1024);
#pragma unroll
    for (int ni = 0; ni < 4; ++ni)
      bfr[ni] = *(const short8*)(sb + bbase + ni*1024);
#pragma unroll
    for (int mi = 0; mi < 4; ++mi)
#pragma unroll
      for (int ni = 0; ni < 4; ++ni)
        acc[mi][ni] = __builtin_amdgcn_mfma_f32_16x16x32_bf16(af[mi], bfr[ni], acc[mi][ni], 0, 0, 0);
  };

  STAGE(0, 0);
  STAGE(1, 32);
  asm volatile("s_waitcnt vmcnt(3)" ::: "memory");
  __builtin_amdgcn_s_barrier();
  __builtin_amdgcn_sched_barrier(0);

  int cur = 0;
  for (int tt = 0; tt < NSTEP-2; ++tt) {
    int stg = cur + 2; if (stg >= 3) stg -= 3;
    STAGE(stg, (tt+2)*32);
    COMPUTE(cur);
    asm volatile("s_waitcnt vmcnt(3)" ::: "memory");
    __builtin_amdgcn_sched_barrier(0);
    __builtin_amdgcn_s_barrier();
    __builtin_amdgcn_sched_barrier(0);
    cur = (cur + 1 == 3) ? 0 : cur + 1;
  }
  COMPUTE(cur);
  asm volatile("s_waitcnt vmcnt(0)" ::: "memory");
  __builtin_amdgcn_sched_barrier(0);
  __builtin_amdgcn_s_barrier();
  __builtin_amdgcn_sched_barrier(0);
  cur = (cur + 1 == 3) ? 0 : cur + 1;
  COMPUTE(cur);

#pragma unroll
  for (int mi = 0; mi < 4; ++mi) {
#pragma unroll
    for (int ni = 0; ni < 4; ++ni) {
      const int gc = c0 + wn*64 + ni*16 + lr;
      const float bias = pb[gc];
#pragma unroll
      for (int r = 0; r < 4; ++r) {
        const int tok = m0 + wm*64 + mi*16 + lk*4 + r;
        if (tok < N_)
          out[((long)b*N_ + tok)*768 + gc] = acc[mi][ni][r] + bias;
      }
    }
  }
}

extern "C" void kernel_launch(void* const* d_in, const int* in_sizes, int n_in,
                              void* d_out, int out_size, void* d_ws, size_t ws_size,
                              hipStream_t stream) {
  const float* x      = (const float*)d_in[0];
  const float* rope   = (const float*)d_in[1];
  const float* qkv_w  = (const float*)d_in[2];
  const float* q_bias = (const float*)d_in[3];
  const float* v_bias = (const float*)d_in[4];
  const float* proj_w = (const float*)d_in[5];
  const float* proj_b = (const float*)d_in[6];
  float* out = (float*)d_out;

  char* w0 = (char*)d_ws;
  unsigned short* x_bf  = (unsigned short*)w0;                        // dead after gemm1
  unsigned short* wq_bf = (unsigned short*)(w0 + 50343936);
  unsigned short* qkv   = (unsigned short*)(w0 + 50343936 + 3538944);
  float*          part  = (float*)w0;                                 // aliases x_bf
  unsigned short* McT   = (unsigned short*)(w0 + 25165824 + 1572864);

  const long n4x = (long)M_TOT*768/4;
  const long n4w = (long)K3*768/4;
  cvt_kernel<<<2048, 256, 0, stream>>>(x, x_bf, qkv_w, wq_bf, n4x, n4x + n4w);

  gemm_qkv_rope<<<2313, 512, 0, stream>>>(x_bf, wq_bf, rope, q_bias, v_bias, qkv);

  kv_partial_kernel<<<dim3(CHUNKS, 96), 256, 0, stream>>>(qkv, part);
  mcomb_kernel<<<384, 256, 0, stream>>>(part, proj_w, McT);

  gemm_final<<<792, 512, 0, stream>>>(qkv, McT, proj_b, out);
}